// Round 4
// baseline (249.607 us; speedup 1.0000x reference)
//
#include <hip/hip_runtime.h>

#define DM 1024
#define NH 16
#define HD 64
#define SEQ 2048
#define BATCH 4
#define MROWS (BATCH*SEQ)   // 8192

typedef short short8 __attribute__((ext_vector_type(8)));
typedef float f32x4 __attribute__((ext_vector_type(4)));
typedef unsigned short u16x8 __attribute__((ext_vector_type(8)));
typedef unsigned short u16x4 __attribute__((ext_vector_type(4)));

__device__ inline unsigned short f2b(float f) {
    union { float f; unsigned u; } v; v.f = f;
    unsigned r = v.u + 0x7fffu + ((v.u >> 16) & 1u);   // RNE
    return (unsigned short)(r >> 16);
}

__device__ inline void gload_lds16(const void* g, void* l) {
    __builtin_amdgcn_global_load_lds(
        (const __attribute__((address_space(1))) void*)g,
        (__attribute__((address_space(3))) void*)l, 16, 0, 0);
}

__device__ inline unsigned cvt_pk_bf16(float lo, float hi) {
    unsigned r;
    asm("v_cvt_pk_bf16_f32 %0, %1, %2" : "=v"(r) : "v"(lo), "v"(hi));
    return r;
}

// ---------------- convert x (fp32 -> bf16) ----------------
__global__ void k_cvt_x(const float* __restrict__ x, unsigned short* __restrict__ xb) {
    long i = ((long)blockIdx.x * 256 + threadIdx.x) * 8;
    float4 a = *reinterpret_cast<const float4*>(x + i);
    float4 b = *reinterpret_cast<const float4*>(x + i + 4);
    u16x8 o;
    o[0]=f2b(a.x); o[1]=f2b(a.y); o[2]=f2b(a.z); o[3]=f2b(a.w);
    o[4]=f2b(b.x); o[5]=f2b(b.y); o[6]=f2b(b.z); o[7]=f2b(b.w);
    *reinterpret_cast<u16x8*>(xb + i) = o;
}

// ---------------- convert + transpose W (fp32 [k][n] -> bf16 [n][k]) ----------------
__global__ void k_cvt_wT(const float* W0, const float* W1, const float* W2, const float* W3,
                         unsigned short* __restrict__ out) {
    const float* Ws[4] = {W0, W1, W2, W3};
    const float* W = Ws[blockIdx.z];
    unsigned short* o = out + (size_t)blockIdx.z * DM * DM;
    __shared__ float t[64][65];
    int tx = threadIdx.x & 15, ty = threadIdx.x >> 4;
    int nb = blockIdx.x * 64, kb = blockIdx.y * 64;
#pragma unroll
    for (int i = 0; i < 4; ++i) {
        int r = ty + 16 * i;
        float4 v = *reinterpret_cast<const float4*>(W + (size_t)(kb + r) * DM + nb + tx * 4);
        t[r][tx*4+0] = v.x; t[r][tx*4+1] = v.y; t[r][tx*4+2] = v.z; t[r][tx*4+3] = v.w;
    }
    __syncthreads();
#pragma unroll
    for (int i = 0; i < 4; ++i) {
        int r = ty + 16 * i;                  // n-local
        u16x4 pv;
#pragma unroll
        for (int j = 0; j < 4; ++j) pv[j] = f2b(t[tx*4+j][r]);
        *reinterpret_cast<u16x4*>(o + (size_t)(nb + r) * DM + kb + tx * 4) = pv;
    }
}

// ---------------- 128x128 bf16 MFMA GEMM ----------------
#define BM 128
#define BN 128
#define BK 64
#define QSCALE 0.1803368801f   // 0.125 * log2(e)

__global__ __launch_bounds__(256) void k_gemm(const unsigned short* __restrict__ A,
                                              const unsigned short* __restrict__ Bt,
                                              const float* __restrict__ bias,
                                              unsigned short* __restrict__ outb,
                                              float* __restrict__ outf, int mode) {
    __shared__ unsigned short lds[BM*BK + BN*BK];   // 32 KB
    unsigned short* lA = lds;
    unsigned short* lB = lds + BM*BK;
    int tid = threadIdx.x, lane = tid & 63, wv = tid >> 6;
    int wr = wv >> 1, wc = wv & 1;
    int c = lane & 15, g = lane >> 4;
    int m0 = blockIdx.x * BM, n0 = blockIdx.y * BN;
    f32x4 acc[4][4] = {};

    for (int kt = 0; kt < DM / BK; ++kt) {
#pragma unroll
        for (int it = 0; it < 4; ++it) {
            int sgi = it * 256 + tid;
            int row = sgi >> 3, blk = sgi & 7;
            int srcoff = kt * BK + ((blk ^ (row & 7)) << 3);
            gload_lds16(A  + (size_t)(m0 + row) * DM + srcoff, &lA[(it*256 + wv*64) * 8]);
            gload_lds16(Bt + (size_t)(n0 + row) * DM + srcoff, &lB[(it*256 + wv*64) * 8]);
        }
        __syncthreads();
#pragma unroll
        for (int ks = 0; ks < 2; ++ks) {
            short8 af[4], bf[4];
#pragma unroll
            for (int mi = 0; mi < 4; ++mi) {
                int row = wr*64 + mi*16 + c;
                af[mi] = *reinterpret_cast<const short8*>(&lA[row*64 + (((ks*4 + g) ^ (row & 7)) << 3)]);
            }
#pragma unroll
            for (int ni = 0; ni < 4; ++ni) {
                int row = wc*64 + ni*16 + c;
                bf[ni] = *reinterpret_cast<const short8*>(&lB[row*64 + (((ks*4 + g) ^ (row & 7)) << 3)]);
            }
#pragma unroll
            for (int mi = 0; mi < 4; ++mi)
#pragma unroll
                for (int ni = 0; ni < 4; ++ni)
                    acc[mi][ni] = __builtin_amdgcn_mfma_f32_16x16x32_bf16(af[mi], bf[ni], acc[mi][ni], 0, 0, 0);
        }
        __syncthreads();
    }

    if (mode <= 1) {                     // Q / K -> [B,H,S,Hd] bf16  (Q pre-scaled)
        float sc = (mode == 0) ? QSCALE : 1.0f;
#pragma unroll
        for (int mi = 0; mi < 4; ++mi)
#pragma unroll
            for (int ni = 0; ni < 4; ++ni)
#pragma unroll
                for (int r = 0; r < 4; ++r) {
                    int gr = m0 + wr*64 + mi*16 + 4*g + r;
                    int gc = n0 + wc*64 + ni*16 + c;
                    float v = (acc[mi][ni][r] + bias[gc]) * sc;
                    int b = gr >> 11, s = gr & 2047, h = gc >> 6, d = gc & 63;
                    outb[(((size_t)(b*NH + h) * SEQ + s) << 6) + d] = f2b(v);
                }
    } else if (mode == 2) {              // V^T -> [B,H,Hd,S] bf16 via LDS transpose
        unsigned short* t = lds;         // 128x128 ushorts = 32 KB exactly
#pragma unroll
        for (int mi = 0; mi < 4; ++mi)
#pragma unroll
            for (int ni = 0; ni < 4; ++ni)
#pragma unroll
                for (int r = 0; r < 4; ++r) {
                    int lr = wr*64 + mi*16 + 4*g + r;   // s-local
                    int lc = wc*64 + ni*16 + c;         // col-local
                    t[lc*128 + lr] = f2b(acc[mi][ni][r] + bias[n0 + lc]);
                }
        __syncthreads();
#pragma unroll
        for (int i = 0; i < 8; ++i) {
            int idx = (i*256 + tid) * 8;          // ushort offset in t
            int lc = idx >> 7, lr = idx & 127;
            int gcol = n0 + lc, grow = m0 + lr;
            int b = grow >> 11, s = grow & 2047, h = gcol >> 6, d = gcol & 63;
            *reinterpret_cast<u16x8*>(&outb[((size_t)((b*NH + h) << 6) + d) * SEQ + s]) =
                *reinterpret_cast<u16x8*>(&t[idx]);
        }
    } else {                             // final fp32 out + bias
#pragma unroll
        for (int mi = 0; mi < 4; ++mi)
#pragma unroll
            for (int ni = 0; ni < 4; ++ni)
#pragma unroll
                for (int r = 0; r < 4; ++r) {
                    int gr = m0 + wr*64 + mi*16 + 4*g + r;
                    int gc = n0 + wc*64 + ni*16 + c;
                    outf[(size_t)gr * DM + gc] = acc[mi][ni][r] + bias[gc];
                }
    }
}

// ---------------- flash attention ----------------
// 4-deep LDS pipeline, counted vmcnt, raw barriers; per-lane deferred max;
// row-sum via ones-MFMA (l lives in an accumulator, no shuffles).
__global__ __launch_bounds__(256) void k_attn(const unsigned short* __restrict__ Q,
                                              const unsigned short* __restrict__ K,
                                              const unsigned short* __restrict__ VT,
                                              unsigned short* __restrict__ AO) {
    __shared__ unsigned short kt[4][64*64], vt[4][64*64];   // 64 KB
    int tid = threadIdx.x, lane = tid & 63, wv = tid >> 6;
    int c = lane & 15, g = lane >> 4;

    // XCD swizzle: 2048 blocks, 8 XCDs -> XCD x gets heads [8x, 8x+8)
    int flat = blockIdx.x;
    int nb = (flat & 7) * 256 + (flat >> 3);
    int qb = nb & 31, bh = nb >> 5;

    const unsigned short* Qh = Q  + (size_t)bh * SEQ * HD;
    const unsigned short* Kh = K  + (size_t)bh * SEQ * HD;
    const unsigned short* Vh = VT + (size_t)bh * HD * SEQ;

    int qrow = qb*64 + wv*16 + c;
    short8 qf[2];
    qf[0] = *reinterpret_cast<const short8*>(&Qh[(size_t)qrow*HD +      g*8]);
    qf[1] = *reinterpret_cast<const short8*>(&Qh[(size_t)qrow*HD + 32 + g*8]);

    // staging addresses (hoisted): rows 0..31 (it0) and 32..63 (it1)
    int row = tid >> 3, blk = tid & 7;
    int xo = (blk ^ (row & 7)) << 3;
    auto srow = [](int r) {
        return ((r >> 4) & 1)*32 + ((r >> 2) & 3)*8 + ((r >> 5) & 1)*4 + (r & 3);
    };
    const unsigned short* gK0 = Kh + (size_t)srow(row)      * HD + xo;
    const unsigned short* gK1 = Kh + (size_t)srow(row + 32) * HD + xo;
    const unsigned short* gV0 = Vh + (size_t)row        * SEQ + xo;
    const unsigned short* gV1 = Vh + (size_t)(row + 32) * SEQ + xo;
    unsigned ldso = wv * 512;

    auto stage = [&](int buf, int t) {
        gload_lds16(gK0 + (size_t)t*64*HD, &kt[buf][ldso]);
        gload_lds16(gK1 + (size_t)t*64*HD, &kt[buf][2048 + ldso]);
        gload_lds16(gV0 + t*64,            &vt[buf][ldso]);
        gload_lds16(gV1 + t*64,            &vt[buf][2048 + ldso]);
    };

    float m = -1e30f;
    f32x4 oacc[4] = {}, lacc = {};
    const short ob = (short)0x3F80;                 // bf16 1.0
    const short8 ones = {ob, ob, ob, ob, ob, ob, ob, ob};

    stage(0, 0); stage(1, 1); stage(2, 2);          // 12 loads in flight

    for (int t = 0; t < SEQ/64; ++t) {
        if (t <= 29)      asm volatile("s_waitcnt vmcnt(8)" ::: "memory");
        else if (t == 30) asm volatile("s_waitcnt vmcnt(4)" ::: "memory");
        else              asm volatile("s_waitcnt vmcnt(0)" ::: "memory");
        __builtin_amdgcn_s_barrier();
        if (t + 3 < SEQ/64) stage((t + 3) & 3, t + 3);
        int cur = t & 3;

        // QK^T swapped: lane (c,g) holds 16 scores for q-row c (log2 domain)
        f32x4 sacc[4] = {};
        __builtin_amdgcn_s_setprio(1);
#pragma unroll
        for (int ks = 0; ks < 2; ++ks)
#pragma unroll
            for (int nt = 0; nt < 4; ++nt) {
                int y = nt*16 + c;
                short8 kf = *reinterpret_cast<const short8*>(
                    &kt[cur][y*64 + (((ks*4 + g) ^ (y & 7)) << 3)]);
                sacc[nt] = __builtin_amdgcn_mfma_f32_16x16x32_bf16(kf, qf[ks], sacc[nt], 0, 0, 0);
            }
        __builtin_amdgcn_s_setprio(0);

        // in-lane tile max only (no shuffles on the common path)
        float t0 = fmaxf(fmaxf(sacc[0][0], sacc[0][1]), fmaxf(sacc[0][2], sacc[0][3]));
        float t1 = fmaxf(fmaxf(sacc[1][0], sacc[1][1]), fmaxf(sacc[1][2], sacc[1][3]));
        float t2 = fmaxf(fmaxf(sacc[2][0], sacc[2][1]), fmaxf(sacc[2][2], sacc[2][3]));
        float t3 = fmaxf(fmaxf(sacc[3][0], sacc[3][1]), fmaxf(sacc[3][2], sacc[3][3]));
        float tm = fmaxf(fmaxf(t0, t1), fmaxf(t2, t3));

        // deferred rescale: only when some lane's max grew past m+8 (log2)
        if (__any(tm > m + 8.0f)) {
            tm = fmaxf(tm, __shfl_xor(tm, 16, 64));
            tm = fmaxf(tm, __shfl_xor(tm, 32, 64));
            float mn = fmaxf(m, tm);
            float corr = __builtin_amdgcn_exp2f(m - mn);
            m = mn;
            lacc *= corr;
#pragma unroll
            for (int ft = 0; ft < 4; ++ft)
#pragma unroll
                for (int r = 0; r < 4; ++r) oacc[ft][r] *= corr;
        }

        // P = exp2(S - m); no per-tile sum (ones-MFMA handles it)
#pragma unroll
        for (int nt = 0; nt < 4; ++nt)
#pragma unroll
            for (int r = 0; r < 4; ++r)
                sacc[nt][r] = __builtin_amdgcn_exp2f(sacc[nt][r] - m);

        // pack P -> bf16 PV A-fragments
        union { unsigned u[4]; short8 v; } U0, U1;
        U0.u[0] = cvt_pk_bf16(sacc[0][0], sacc[0][1]);
        U0.u[1] = cvt_pk_bf16(sacc[0][2], sacc[0][3]);
        U0.u[2] = cvt_pk_bf16(sacc[2][0], sacc[2][1]);
        U0.u[3] = cvt_pk_bf16(sacc[2][2], sacc[2][3]);
        U1.u[0] = cvt_pk_bf16(sacc[1][0], sacc[1][1]);
        U1.u[1] = cvt_pk_bf16(sacc[1][2], sacc[1][3]);
        U1.u[2] = cvt_pk_bf16(sacc[3][0], sacc[3][1]);
        U1.u[3] = cvt_pk_bf16(sacc[3][2], sacc[3][3]);
        short8 pa0 = U0.v, pa1 = U1.v;

        // PV swapped + row-sum (ones) into lacc
        __builtin_amdgcn_s_setprio(1);
#pragma unroll
        for (int ft = 0; ft < 4; ++ft) {
            int y = ft*16 + c;
            short8 vf0 = *reinterpret_cast<const short8*>(
                &vt[cur][y*64 + ((g ^ (y & 7)) << 3)]);
            short8 vf1 = *reinterpret_cast<const short8*>(
                &vt[cur][y*64 + (((4 + g) ^ (y & 7)) << 3)]);
            oacc[ft] = __builtin_amdgcn_mfma_f32_16x16x32_bf16(vf0, pa0, oacc[ft], 0, 0, 0);
            oacc[ft] = __builtin_amdgcn_mfma_f32_16x16x32_bf16(vf1, pa1, oacc[ft], 0, 0, 0);
        }
        lacc = __builtin_amdgcn_mfma_f32_16x16x32_bf16(ones, pa0, lacc, 0, 0, 0);
        lacc = __builtin_amdgcn_mfma_f32_16x16x32_bf16(ones, pa1, lacc, 0, 0, 0);
        __builtin_amdgcn_s_setprio(0);
    }

    int b = bh >> 4, h = bh & 15;
    float inv = 1.f / lacc[0];
#pragma unroll
    for (int ft = 0; ft < 4; ++ft) {
        u16x4 o4;
#pragma unroll
        for (int r = 0; r < 4; ++r) o4[r] = f2b(oacc[ft][r] * inv);
        *reinterpret_cast<u16x4*>(
            &AO[(size_t)(b*SEQ + qrow) * DM + h*HD + ft*16 + 4*g]) = o4;
    }
}

extern "C" void kernel_launch(void* const* d_in, const int* in_sizes, int n_in,
                              void* d_out, int out_size, void* d_ws, size_t ws_size,
                              hipStream_t stream) {
    const float* x  = (const float*)d_in[0];
    const float* Wq = (const float*)d_in[1];
    const float* bq = (const float*)d_in[2];
    const float* Wk = (const float*)d_in[3];
    const float* bk = (const float*)d_in[4];
    const float* Wv = (const float*)d_in[5];
    const float* bv = (const float*)d_in[6];
    const float* Wo = (const float*)d_in[7];
    const float* bo = (const float*)d_in[8];

    char* ws = (char*)d_ws;
    unsigned short* xb  = (unsigned short*)(ws);                  // 16 MB
    unsigned short* wT  = (unsigned short*)(ws + (16u<<20));      //  8 MB (4 mats)
    unsigned short* Qb  = (unsigned short*)(ws + (24u<<20));      // 16 MB
    unsigned short* Kb  = (unsigned short*)(ws + (40u<<20));      // 16 MB
    unsigned short* VTb = (unsigned short*)(ws + (56u<<20));      // 16 MB
    unsigned short* AOb = (unsigned short*)(ws + (72u<<20));      // 16 MB

    k_cvt_x<<<dim3(MROWS*DM/8/256), 256, 0, stream>>>(x, xb);
    k_cvt_wT<<<dim3(16,16,4), 256, 0, stream>>>(Wq, Wk, Wv, Wo, wT);

    k_gemm<<<dim3(MROWS/BM, DM/BN), 256, 0, stream>>>(xb, wT,            bq, Qb,  nullptr, 0);
    k_gemm<<<dim3(MROWS/BM, DM/BN), 256, 0, stream>>>(xb, wT + DM*DM,    bk, Kb,  nullptr, 1);
    k_gemm<<<dim3(MROWS/BM, DM/BN), 256, 0, stream>>>(xb, wT + 2*DM*DM,  bv, VTb, nullptr, 2);

    k_attn<<<dim3(SEQ/64 * BATCH*NH), 256, 0, stream>>>(Qb, Kb, VTb, AOb);

    k_gemm<<<dim3(MROWS/BM, DM/BN), 256, 0, stream>>>(AOb, wT + 3*DM*DM, bo, nullptr, (float*)d_out, 3);
}

// Round 7
// 210.154 us; speedup vs baseline: 1.1877x; 1.1877x over previous
//
#include <hip/hip_runtime.h>

#define DM 1024
#define NH 16
#define HD 64
#define SEQ 2048
#define BATCH 4
#define MROWS (BATCH*SEQ)   // 8192

typedef short short8 __attribute__((ext_vector_type(8)));
typedef float f32x4 __attribute__((ext_vector_type(4)));
typedef unsigned short u16x8 __attribute__((ext_vector_type(8)));
typedef unsigned short u16x4 __attribute__((ext_vector_type(4)));

__device__ inline unsigned short f2b(float f) {
    union { float f; unsigned u; } v; v.f = f;
    unsigned r = v.u + 0x7fffu + ((v.u >> 16) & 1u);   // RNE
    return (unsigned short)(r >> 16);
}

__device__ inline void gload_lds16(const void* g, void* l) {
    __builtin_amdgcn_global_load_lds(
        (const __attribute__((address_space(1))) void*)g,
        (__attribute__((address_space(3))) void*)l, 16, 0, 0);
}

__device__ inline unsigned cvt_pk_bf16(float lo, float hi) {
    unsigned r;
    asm("v_cvt_pk_bf16_f32 %0, %1, %2" : "=v"(r) : "v"(lo), "v"(hi));
    return r;
}

// ---------------- convert x (fp32 -> bf16) ----------------
__global__ void k_cvt_x(const float* __restrict__ x, unsigned short* __restrict__ xb) {
    long i = ((long)blockIdx.x * 256 + threadIdx.x) * 8;
    float4 a = *reinterpret_cast<const float4*>(x + i);
    float4 b = *reinterpret_cast<const float4*>(x + i + 4);
    u16x8 o;
    o[0]=f2b(a.x); o[1]=f2b(a.y); o[2]=f2b(a.z); o[3]=f2b(a.w);
    o[4]=f2b(b.x); o[5]=f2b(b.y); o[6]=f2b(b.z); o[7]=f2b(b.w);
    *reinterpret_cast<u16x8*>(xb + i) = o;
}

// ---------------- convert + transpose W (fp32 [k][n] -> bf16 [n][k]) ----------------
__global__ void k_cvt_wT(const float* W0, const float* W1, const float* W2, const float* W3,
                         unsigned short* __restrict__ out) {
    const float* Ws[4] = {W0, W1, W2, W3};
    const float* W = Ws[blockIdx.z];
    unsigned short* o = out + (size_t)blockIdx.z * DM * DM;
    __shared__ float t[64][65];
    int tx = threadIdx.x & 15, ty = threadIdx.x >> 4;
    int nb = blockIdx.x * 64, kb = blockIdx.y * 64;
#pragma unroll
    for (int i = 0; i < 4; ++i) {
        int r = ty + 16 * i;
        float4 v = *reinterpret_cast<const float4*>(W + (size_t)(kb + r) * DM + nb + tx * 4);
        t[r][tx*4+0] = v.x; t[r][tx*4+1] = v.y; t[r][tx*4+2] = v.z; t[r][tx*4+3] = v.w;
    }
    __syncthreads();
#pragma unroll
    for (int i = 0; i < 4; ++i) {
        int r = ty + 16 * i;                  // n-local
        u16x4 pv;
#pragma unroll
        for (int j = 0; j < 4; ++j) pv[j] = f2b(t[tx*4+j][r]);
        *reinterpret_cast<u16x4*>(o + (size_t)(nb + r) * DM + kb + tx * 4) = pv;
    }
}

// ---------------- 128x128 bf16 MFMA GEMM ----------------
#define BM 128
#define BN 128
#define BK 64
#define QSCALE 0.1803368801f   // 0.125 * log2(e)

// Merged QKV GEMM: Bt = wT (Wq^T|Wk^T|Wv^T contiguous), N = 3072.
// Epilogue switches on n0>>10: 0 -> Q [B,H,S,Hd] (pre-scaled), 1 -> K, 2 -> V^T [B,H,Hd,S].
__global__ __launch_bounds__(256) void k_gemm_qkv(const unsigned short* __restrict__ A,
                                                  const unsigned short* __restrict__ WT,
                                                  const float* __restrict__ bq,
                                                  const float* __restrict__ bk,
                                                  const float* __restrict__ bv,
                                                  unsigned short* __restrict__ Qb,
                                                  unsigned short* __restrict__ Kb,
                                                  unsigned short* __restrict__ VTb) {
    __shared__ unsigned short lds[BM*BK + BN*BK];   // 32 KB
    unsigned short* lA = lds;
    unsigned short* lB = lds + BM*BK;
    int tid = threadIdx.x, lane = tid & 63, wv = tid >> 6;
    int wr = wv >> 1, wc = wv & 1;
    int c = lane & 15, g = lane >> 4;
    int m0 = blockIdx.x * BM, n0 = blockIdx.y * BN;
    f32x4 acc[4][4] = {};

    for (int kt = 0; kt < DM / BK; ++kt) {
#pragma unroll
        for (int it = 0; it < 4; ++it) {
            int sgi = it * 256 + tid;
            int row = sgi >> 3, blk = sgi & 7;
            int srcoff = kt * BK + ((blk ^ (row & 7)) << 3);
            gload_lds16(A  + (size_t)(m0 + row) * DM + srcoff, &lA[(it*256 + wv*64) * 8]);
            gload_lds16(WT + (size_t)(n0 + row) * DM + srcoff, &lB[(it*256 + wv*64) * 8]);
        }
        __syncthreads();
#pragma unroll
        for (int ks = 0; ks < 2; ++ks) {
            short8 af[4], bf[4];
#pragma unroll
            for (int mi = 0; mi < 4; ++mi) {
                int row = wr*64 + mi*16 + c;
                af[mi] = *reinterpret_cast<const short8*>(&lA[row*64 + (((ks*4 + g) ^ (row & 7)) << 3)]);
            }
#pragma unroll
            for (int ni = 0; ni < 4; ++ni) {
                int row = wc*64 + ni*16 + c;
                bf[ni] = *reinterpret_cast<const short8*>(&lB[row*64 + (((ks*4 + g) ^ (row & 7)) << 3)]);
            }
#pragma unroll
            for (int mi = 0; mi < 4; ++mi)
#pragma unroll
                for (int ni = 0; ni < 4; ++ni)
                    acc[mi][ni] = __builtin_amdgcn_mfma_f32_16x16x32_bf16(af[mi], bf[ni], acc[mi][ni], 0, 0, 0);
        }
        __syncthreads();
    }

    int mat = n0 >> 10;                       // 0=Q 1=K 2=V (block-uniform)
    int gb = n0 & 1023;                       // column base within the mat
    const float* bias = (mat == 0) ? bq : (mat == 1) ? bk : bv;

    if (mat < 2) {                            // Q / K -> [B,H,S,Hd] bf16 (Q pre-scaled)
        unsigned short* outb = (mat == 0) ? Qb : Kb;
        float sc = (mat == 0) ? QSCALE : 1.0f;
#pragma unroll
        for (int mi = 0; mi < 4; ++mi)
#pragma unroll
            for (int ni = 0; ni < 4; ++ni)
#pragma unroll
                for (int r = 0; r < 4; ++r) {
                    int gr = m0 + wr*64 + mi*16 + 4*g + r;
                    int gc = gb + wc*64 + ni*16 + c;
                    float v = (acc[mi][ni][r] + bias[gc]) * sc;
                    int b = gr >> 11, s = gr & 2047, h = gc >> 6, d = gc & 63;
                    outb[(((size_t)(b*NH + h) * SEQ + s) << 6) + d] = f2b(v);
                }
    } else {                                  // V^T -> [B,H,Hd,S] bf16 via LDS transpose
        unsigned short* t = lds;              // 128x128 ushorts = 32 KB exactly
#pragma unroll
        for (int mi = 0; mi < 4; ++mi)
#pragma unroll
            for (int ni = 0; ni < 4; ++ni)
#pragma unroll
                for (int r = 0; r < 4; ++r) {
                    int lr = wr*64 + mi*16 + 4*g + r;   // s-local
                    int lc = wc*64 + ni*16 + c;         // col-local
                    t[lc*128 + lr] = f2b(acc[mi][ni][r] + bias[gb + lc]);
                }
        __syncthreads();
#pragma unroll
        for (int i = 0; i < 8; ++i) {
            int idx = (i*256 + tid) * 8;          // ushort offset in t
            int lc = idx >> 7, lr = idx & 127;
            int gcol = gb + lc, grow = m0 + lr;
            int b = grow >> 11, s = grow & 2047, h = gcol >> 6, d = gcol & 63;
            *reinterpret_cast<u16x8*>(&VTb[((size_t)((b*NH + h) << 6) + d) * SEQ + s]) =
                *reinterpret_cast<u16x8*>(&t[idx]);
        }
    }
}

// Final projection GEMM: out fp32 + bias
__global__ __launch_bounds__(256) void k_gemm_o(const unsigned short* __restrict__ A,
                                                const unsigned short* __restrict__ Bt,
                                                const float* __restrict__ bias,
                                                float* __restrict__ outf) {
    __shared__ unsigned short lds[BM*BK + BN*BK];   // 32 KB
    unsigned short* lA = lds;
    unsigned short* lB = lds + BM*BK;
    int tid = threadIdx.x, lane = tid & 63, wv = tid >> 6;
    int wr = wv >> 1, wc = wv & 1;
    int c = lane & 15, g = lane >> 4;
    int m0 = blockIdx.x * BM, n0 = blockIdx.y * BN;
    f32x4 acc[4][4] = {};

    for (int kt = 0; kt < DM / BK; ++kt) {
#pragma unroll
        for (int it = 0; it < 4; ++it) {
            int sgi = it * 256 + tid;
            int row = sgi >> 3, blk = sgi & 7;
            int srcoff = kt * BK + ((blk ^ (row & 7)) << 3);
            gload_lds16(A  + (size_t)(m0 + row) * DM + srcoff, &lA[(it*256 + wv*64) * 8]);
            gload_lds16(Bt + (size_t)(n0 + row) * DM + srcoff, &lB[(it*256 + wv*64) * 8]);
        }
        __syncthreads();
#pragma unroll
        for (int ks = 0; ks < 2; ++ks) {
            short8 af[4], bf[4];
#pragma unroll
            for (int mi = 0; mi < 4; ++mi) {
                int row = wr*64 + mi*16 + c;
                af[mi] = *reinterpret_cast<const short8*>(&lA[row*64 + (((ks*4 + g) ^ (row & 7)) << 3)]);
            }
#pragma unroll
            for (int ni = 0; ni < 4; ++ni) {
                int row = wc*64 + ni*16 + c;
                bf[ni] = *reinterpret_cast<const short8*>(&lB[row*64 + (((ks*4 + g) ^ (row & 7)) << 3)]);
            }
#pragma unroll
            for (int mi = 0; mi < 4; ++mi)
#pragma unroll
                for (int ni = 0; ni < 4; ++ni)
                    acc[mi][ni] = __builtin_amdgcn_mfma_f32_16x16x32_bf16(af[mi], bf[ni], acc[mi][ni], 0, 0, 0);
        }
        __syncthreads();
    }

#pragma unroll
    for (int mi = 0; mi < 4; ++mi)
#pragma unroll
        for (int ni = 0; ni < 4; ++ni)
#pragma unroll
            for (int r = 0; r < 4; ++r) {
                int gr = m0 + wr*64 + mi*16 + 4*g + r;
                int gc = n0 + wc*64 + ni*16 + c;
                outf[(size_t)gr * DM + gc] = acc[mi][ni][r] + bias[gc];
            }
}

// ---------------- flash attention ----------------
// Round-3 skeleton (2-buffer, __syncthreads, stage-at-top) + round-4-validated
// softmax: per-lane deferred max, ones-MFMA row-sum, hoisted stage pointers.
// 4 waves x 16 q-rows; KV tile 64; 2048 blocks XCD-swizzled.
__global__ __launch_bounds__(256) void k_attn(const unsigned short* __restrict__ Q,
                                              const unsigned short* __restrict__ K,
                                              const unsigned short* __restrict__ VT,
                                              unsigned short* __restrict__ AO) {
    __shared__ unsigned short kt[2][64*64], vt[2][64*64];   // 32 KB
    int tid = threadIdx.x, lane = tid & 63, wv = tid >> 6;
    int c = lane & 15, g = lane >> 4;

    // XCD swizzle: 2048 blocks, 8 XCDs -> XCD x gets heads [8x, 8x+8)
    int flat = blockIdx.x;
    int nb = (flat & 7) * 256 + (flat >> 3);
    int qb = nb & 31, bh = nb >> 5;

    const unsigned short* Qh = Q  + (size_t)bh * SEQ * HD;
    const unsigned short* Kh = K  + (size_t)bh * SEQ * HD;
    const unsigned short* Vh = VT + (size_t)bh * HD * SEQ;

    int qrow = qb*64 + wv*16 + c;
    short8 qf[2];
    qf[0] = *reinterpret_cast<const short8*>(&Qh[(size_t)qrow*HD +      g*8]);
    qf[1] = *reinterpret_cast<const short8*>(&Qh[(size_t)qrow*HD + 32 + g*8]);

    // staging addresses (hoisted): rows 0..31 and 32..63
    int row = tid >> 3, blk = tid & 7;
    int xo = (blk ^ (row & 7)) << 3;
    auto srow = [](int r) {
        return ((r >> 4) & 1)*32 + ((r >> 2) & 3)*8 + ((r >> 5) & 1)*4 + (r & 3);
    };
    const unsigned short* gK0 = Kh + (size_t)srow(row)      * HD + xo;
    const unsigned short* gK1 = Kh + (size_t)srow(row + 32) * HD + xo;
    const unsigned short* gV0 = Vh + (size_t)row        * SEQ + xo;
    const unsigned short* gV1 = Vh + (size_t)(row + 32) * SEQ + xo;
    unsigned ldso = wv * 512;

    auto stage = [&](int buf, int t) {
        gload_lds16(gK0 + (size_t)t*64*HD, &kt[buf][ldso]);
        gload_lds16(gK1 + (size_t)t*64*HD, &kt[buf][2048 + ldso]);
        gload_lds16(gV0 + t*64,            &vt[buf][ldso]);
        gload_lds16(gV1 + t*64,            &vt[buf][2048 + ldso]);
    };

    float m = -1e30f;
    f32x4 oacc[4] = {}, lacc = {};
    const short ob = (short)0x3F80;                 // bf16 1.0
    const short8 ones = {ob, ob, ob, ob, ob, ob, ob, ob};

    stage(0, 0);
    __syncthreads();

    int cur = 0;
    const int NT = SEQ/64;
    for (int t = 0; t < NT; ++t) {
        if (t + 1 < NT) stage(cur ^ 1, t + 1);

        // QK^T swapped: lane (c,g) holds 16 scores for q-row c (log2 domain)
        f32x4 sacc[4] = {};
        __builtin_amdgcn_s_setprio(1);
#pragma unroll
        for (int ks = 0; ks < 2; ++ks)
#pragma unroll
            for (int nt = 0; nt < 4; ++nt) {
                int y = nt*16 + c;
                short8 kf = *reinterpret_cast<const short8*>(
                    &kt[cur][y*64 + (((ks*4 + g) ^ (y & 7)) << 3)]);
                sacc[nt] = __builtin_amdgcn_mfma_f32_16x16x32_bf16(kf, qf[ks], sacc[nt], 0, 0, 0);
            }
        __builtin_amdgcn_s_setprio(0);

        // in-lane tile max only (shuffles moved inside the rare rescale branch)
        float t0 = fmaxf(fmaxf(sacc[0][0], sacc[0][1]), fmaxf(sacc[0][2], sacc[0][3]));
        float t1 = fmaxf(fmaxf(sacc[1][0], sacc[1][1]), fmaxf(sacc[1][2], sacc[1][3]));
        float t2 = fmaxf(fmaxf(sacc[2][0], sacc[2][1]), fmaxf(sacc[2][2], sacc[2][3]));
        float t3 = fmaxf(fmaxf(sacc[3][0], sacc[3][1]), fmaxf(sacc[3][2], sacc[3][3]));
        float tm = fmaxf(fmaxf(t0, t1), fmaxf(t2, t3));

        if (__any(tm > m + 8.0f)) {
            tm = fmaxf(tm, __shfl_xor(tm, 16, 64));
            tm = fmaxf(tm, __shfl_xor(tm, 32, 64));
            float mn = fmaxf(m, tm);
            float corr = __builtin_amdgcn_exp2f(m - mn);
            m = mn;
            lacc *= corr;
#pragma unroll
            for (int ft = 0; ft < 4; ++ft)
#pragma unroll
                for (int r = 0; r < 4; ++r) oacc[ft][r] *= corr;
        }

        // P = exp2(S - m); row-sum handled by ones-MFMA
#pragma unroll
        for (int nt = 0; nt < 4; ++nt)
#pragma unroll
            for (int r = 0; r < 4; ++r)
                sacc[nt][r] = __builtin_amdgcn_exp2f(sacc[nt][r] - m);

        // pack P -> bf16 PV A-fragments
        union { unsigned u[4]; short8 v; } U0, U1;
        U0.u[0] = cvt_pk_bf16(sacc[0][0], sacc[0][1]);
        U0.u[1] = cvt_pk_bf16(sacc[0][2], sacc[0][3]);
        U0.u[2] = cvt_pk_bf16(sacc[2][0], sacc[2][1]);
        U0.u[3] = cvt_pk_bf16(sacc[2][2], sacc[2][3]);
        U1.u[0] = cvt_pk_bf16(sacc[1][0], sacc[1][1]);
        U1.u[1] = cvt_pk_bf16(sacc[1][2], sacc[1][3]);
        U1.u[2] = cvt_pk_bf16(sacc[3][0], sacc[3][1]);
        U1.u[3] = cvt_pk_bf16(sacc[3][2], sacc[3][3]);
        short8 pa0 = U0.v, pa1 = U1.v;

        // PV swapped + ones-MFMA row-sum into lacc
        __builtin_amdgcn_s_setprio(1);
#pragma unroll
        for (int ft = 0; ft < 4; ++ft) {
            int y = ft*16 + c;
            short8 vf0 = *reinterpret_cast<const short8*>(
                &vt[cur][y*64 + ((g ^ (y & 7)) << 3)]);
            short8 vf1 = *reinterpret_cast<const short8*>(
                &vt[cur][y*64 + (((4 + g) ^ (y & 7)) << 3)]);
            oacc[ft] = __builtin_amdgcn_mfma_f32_16x16x32_bf16(vf0, pa0, oacc[ft], 0, 0, 0);
            oacc[ft] = __builtin_amdgcn_mfma_f32_16x16x32_bf16(vf1, pa1, oacc[ft], 0, 0, 0);
        }
        lacc = __builtin_amdgcn_mfma_f32_16x16x32_bf16(ones, pa0, lacc, 0, 0, 0);
        lacc = __builtin_amdgcn_mfma_f32_16x16x32_bf16(ones, pa1, lacc, 0, 0, 0);
        __builtin_amdgcn_s_setprio(0);

        __syncthreads();
        cur ^= 1;
    }

    int b = bh >> 4, h = bh & 15;
    float inv = 1.f / lacc[0];
#pragma unroll
    for (int ft = 0; ft < 4; ++ft) {
        u16x4 o4;
#pragma unroll
        for (int r = 0; r < 4; ++r) o4[r] = f2b(oacc[ft][r] * inv);
        *reinterpret_cast<u16x4*>(
            &AO[(size_t)(b*SEQ + qrow) * DM + h*HD + ft*16 + 4*g]) = o4;
    }
}

extern "C" void kernel_launch(void* const* d_in, const int* in_sizes, int n_in,
                              void* d_out, int out_size, void* d_ws, size_t ws_size,
                              hipStream_t stream) {
    const float* x  = (const float*)d_in[0];
    const float* Wq = (const float*)d_in[1];
    const float* bq = (const float*)d_in[2];
    const float* Wk = (const float*)d_in[3];
    const float* bk = (const float*)d_in[4];
    const float* Wv = (const float*)d_in[5];
    const float* bv = (const float*)d_in[6];
    const float* Wo = (const float*)d_in[7];
    const float* bo = (const float*)d_in[8];

    char* ws = (char*)d_ws;
    unsigned short* xb  = (unsigned short*)(ws);                  // 16 MB
    unsigned short* wT  = (unsigned short*)(ws + (16u<<20));      //  8 MB (4 mats)
    unsigned short* Qb  = (unsigned short*)(ws + (24u<<20));      // 16 MB
    unsigned short* Kb  = (unsigned short*)(ws + (40u<<20));      // 16 MB
    unsigned short* VTb = (unsigned short*)(ws + (56u<<20));      // 16 MB
    unsigned short* AOb = (unsigned short*)(ws + (72u<<20));      // 16 MB

    k_cvt_x<<<dim3(MROWS*DM/8/256), 256, 0, stream>>>(x, xb);
    k_cvt_wT<<<dim3(16,16,4), 256, 0, stream>>>(Wq, Wk, Wv, Wo, wT);

    k_gemm_qkv<<<dim3(MROWS/BM, 3*DM/BN), 256, 0, stream>>>(xb, wT, bq, bk, bv, Qb, Kb, VTb);

    k_attn<<<dim3(SEQ/64 * BATCH*NH), 256, 0, stream>>>(Qb, Kb, VTb, AOb);

    k_gemm_o<<<dim3(MROWS/BM, DM/BN), 256, 0, stream>>>(AOb, wT + 3*DM*DM, bo, (float*)d_out);
}

// Round 8
// 199.647 us; speedup vs baseline: 1.2502x; 1.0526x over previous
//
#include <hip/hip_runtime.h>

#define DM 1024
#define NH 16
#define HD 64
#define SEQ 2048
#define BATCH 4
#define MROWS (BATCH*SEQ)   // 8192

typedef short short8 __attribute__((ext_vector_type(8)));
typedef float f32x4 __attribute__((ext_vector_type(4)));
typedef unsigned short u16x8 __attribute__((ext_vector_type(8)));
typedef unsigned short u16x4 __attribute__((ext_vector_type(4)));

__device__ inline unsigned short f2b(float f) {
    union { float f; unsigned u; } v; v.f = f;
    unsigned r = v.u + 0x7fffu + ((v.u >> 16) & 1u);   // RNE
    return (unsigned short)(r >> 16);
}

__device__ inline void gload_lds16(const void* g, void* l) {
    __builtin_amdgcn_global_load_lds(
        (const __attribute__((address_space(1))) void*)g,
        (__attribute__((address_space(3))) void*)l, 16, 0, 0);
}

__device__ inline unsigned cvt_pk_bf16(float lo, float hi) {
    unsigned r;
    asm("v_cvt_pk_bf16_f32 %0, %1, %2" : "=v"(r) : "v"(lo), "v"(hi));
    return r;
}

// ---------------- convert x (fp32 -> bf16) ----------------
__global__ void k_cvt_x(const float* __restrict__ x, unsigned short* __restrict__ xb) {
    long i = ((long)blockIdx.x * 256 + threadIdx.x) * 8;
    float4 a = *reinterpret_cast<const float4*>(x + i);
    float4 b = *reinterpret_cast<const float4*>(x + i + 4);
    u16x8 o;
    o[0]=f2b(a.x); o[1]=f2b(a.y); o[2]=f2b(a.z); o[3]=f2b(a.w);
    o[4]=f2b(b.x); o[5]=f2b(b.y); o[6]=f2b(b.z); o[7]=f2b(b.w);
    *reinterpret_cast<u16x8*>(xb + i) = o;
}

// ---------------- convert + transpose W (fp32 [k][n] -> bf16 [n][k]) ----------------
__global__ void k_cvt_wT(const float* W0, const float* W1, const float* W2, const float* W3,
                         unsigned short* __restrict__ out) {
    const float* Ws[4] = {W0, W1, W2, W3};
    const float* W = Ws[blockIdx.z];
    unsigned short* o = out + (size_t)blockIdx.z * DM * DM;
    __shared__ float t[64][65];
    int tx = threadIdx.x & 15, ty = threadIdx.x >> 4;
    int nb = blockIdx.x * 64, kb = blockIdx.y * 64;
#pragma unroll
    for (int i = 0; i < 4; ++i) {
        int r = ty + 16 * i;
        float4 v = *reinterpret_cast<const float4*>(W + (size_t)(kb + r) * DM + nb + tx * 4);
        t[r][tx*4+0] = v.x; t[r][tx*4+1] = v.y; t[r][tx*4+2] = v.z; t[r][tx*4+3] = v.w;
    }
    __syncthreads();
#pragma unroll
    for (int i = 0; i < 4; ++i) {
        int r = ty + 16 * i;                  // n-local
        u16x4 pv;
#pragma unroll
        for (int j = 0; j < 4; ++j) pv[j] = f2b(t[tx*4+j][r]);
        *reinterpret_cast<u16x4*>(o + (size_t)(nb + r) * DM + kb + tx * 4) = pv;
    }
}

// ---------------- 128x128 bf16 MFMA GEMM ----------------
#define BM 128
#define BN 128
#define BK 64
#define QSCALE 0.1803368801f   // 0.125 * log2(e)

// Merged QKV GEMM: Bt = wT (Wq^T|Wk^T|Wv^T contiguous), N = 3072.
__global__ __launch_bounds__(256) void k_gemm_qkv(const unsigned short* __restrict__ A,
                                                  const unsigned short* __restrict__ WT,
                                                  const float* __restrict__ bq,
                                                  const float* __restrict__ bk,
                                                  const float* __restrict__ bv,
                                                  unsigned short* __restrict__ Qb,
                                                  unsigned short* __restrict__ Kb,
                                                  unsigned short* __restrict__ VTb) {
    __shared__ unsigned short lds[BM*BK + BN*BK];   // 32 KB
    unsigned short* lA = lds;
    unsigned short* lB = lds + BM*BK;
    int tid = threadIdx.x, lane = tid & 63, wv = tid >> 6;
    int wr = wv >> 1, wc = wv & 1;
    int c = lane & 15, g = lane >> 4;
    int m0 = blockIdx.x * BM, n0 = blockIdx.y * BN;
    f32x4 acc[4][4] = {};

    for (int kt = 0; kt < DM / BK; ++kt) {
#pragma unroll
        for (int it = 0; it < 4; ++it) {
            int sgi = it * 256 + tid;
            int row = sgi >> 3, blk = sgi & 7;
            int srcoff = kt * BK + ((blk ^ (row & 7)) << 3);
            gload_lds16(A  + (size_t)(m0 + row) * DM + srcoff, &lA[(it*256 + wv*64) * 8]);
            gload_lds16(WT + (size_t)(n0 + row) * DM + srcoff, &lB[(it*256 + wv*64) * 8]);
        }
        __syncthreads();
#pragma unroll
        for (int ks = 0; ks < 2; ++ks) {
            short8 af[4], bf[4];
#pragma unroll
            for (int mi = 0; mi < 4; ++mi) {
                int row = wr*64 + mi*16 + c;
                af[mi] = *reinterpret_cast<const short8*>(&lA[row*64 + (((ks*4 + g) ^ (row & 7)) << 3)]);
            }
#pragma unroll
            for (int ni = 0; ni < 4; ++ni) {
                int row = wc*64 + ni*16 + c;
                bf[ni] = *reinterpret_cast<const short8*>(&lB[row*64 + (((ks*4 + g) ^ (row & 7)) << 3)]);
            }
#pragma unroll
            for (int mi = 0; mi < 4; ++mi)
#pragma unroll
                for (int ni = 0; ni < 4; ++ni)
                    acc[mi][ni] = __builtin_amdgcn_mfma_f32_16x16x32_bf16(af[mi], bf[ni], acc[mi][ni], 0, 0, 0);
        }
        __syncthreads();
    }

    int mat = n0 >> 10;                       // 0=Q 1=K 2=V (block-uniform)
    int gb = n0 & 1023;                       // column base within the mat
    const float* bias = (mat == 0) ? bq : (mat == 1) ? bk : bv;

    if (mat < 2) {                            // Q / K -> [B,H,S,Hd] bf16 (Q pre-scaled)
        unsigned short* outb = (mat == 0) ? Qb : Kb;
        float sc = (mat == 0) ? QSCALE : 1.0f;
#pragma unroll
        for (int mi = 0; mi < 4; ++mi)
#pragma unroll
            for (int ni = 0; ni < 4; ++ni)
#pragma unroll
                for (int r = 0; r < 4; ++r) {
                    int gr = m0 + wr*64 + mi*16 + 4*g + r;
                    int gc = gb + wc*64 + ni*16 + c;
                    float v = (acc[mi][ni][r] + bias[gc]) * sc;
                    int b = gr >> 11, s = gr & 2047, h = gc >> 6, d = gc & 63;
                    outb[(((size_t)(b*NH + h) * SEQ + s) << 6) + d] = f2b(v);
                }
    } else {                                  // V^T -> [B,H,Hd,S] bf16 via LDS transpose
        unsigned short* t = lds;              // 128x128 ushorts = 32 KB exactly
#pragma unroll
        for (int mi = 0; mi < 4; ++mi)
#pragma unroll
            for (int ni = 0; ni < 4; ++ni)
#pragma unroll
                for (int r = 0; r < 4; ++r) {
                    int lr = wr*64 + mi*16 + 4*g + r;   // s-local
                    int lc = wc*64 + ni*16 + c;         // col-local
                    t[lc*128 + lr] = f2b(acc[mi][ni][r] + bias[gb + lc]);
                }
        __syncthreads();
#pragma unroll
        for (int i = 0; i < 8; ++i) {
            int idx = (i*256 + tid) * 8;          // ushort offset in t
            int lc = idx >> 7, lr = idx & 127;
            int gcol = gb + lc, grow = m0 + lr;
            int b = grow >> 11, s = grow & 2047, h = gcol >> 6, d = gcol & 63;
            *reinterpret_cast<u16x8*>(&VTb[((size_t)((b*NH + h) << 6) + d) * SEQ + s]) =
                *reinterpret_cast<u16x8*>(&t[idx]);
        }
    }
}

// Final projection GEMM: out fp32 + bias
__global__ __launch_bounds__(256) void k_gemm_o(const unsigned short* __restrict__ A,
                                                const unsigned short* __restrict__ Bt,
                                                const float* __restrict__ bias,
                                                float* __restrict__ outf) {
    __shared__ unsigned short lds[BM*BK + BN*BK];   // 32 KB
    unsigned short* lA = lds;
    unsigned short* lB = lds + BM*BK;
    int tid = threadIdx.x, lane = tid & 63, wv = tid >> 6;
    int wr = wv >> 1, wc = wv & 1;
    int c = lane & 15, g = lane >> 4;
    int m0 = blockIdx.x * BM, n0 = blockIdx.y * BN;
    f32x4 acc[4][4] = {};

    for (int kt = 0; kt < DM / BK; ++kt) {
#pragma unroll
        for (int it = 0; it < 4; ++it) {
            int sgi = it * 256 + tid;
            int row = sgi >> 3, blk = sgi & 7;
            int srcoff = kt * BK + ((blk ^ (row & 7)) << 3);
            gload_lds16(A  + (size_t)(m0 + row) * DM + srcoff, &lA[(it*256 + wv*64) * 8]);
            gload_lds16(Bt + (size_t)(n0 + row) * DM + srcoff, &lB[(it*256 + wv*64) * 8]);
        }
        __syncthreads();
#pragma unroll
        for (int ks = 0; ks < 2; ++ks) {
            short8 af[4], bf[4];
#pragma unroll
            for (int mi = 0; mi < 4; ++mi) {
                int row = wr*64 + mi*16 + c;
                af[mi] = *reinterpret_cast<const short8*>(&lA[row*64 + (((ks*4 + g) ^ (row & 7)) << 3)]);
            }
#pragma unroll
            for (int ni = 0; ni < 4; ++ni) {
                int row = wc*64 + ni*16 + c;
                bf[ni] = *reinterpret_cast<const short8*>(&lB[row*64 + (((ks*4 + g) ^ (row & 7)) << 3)]);
            }
#pragma unroll
            for (int mi = 0; mi < 4; ++mi)
#pragma unroll
                for (int ni = 0; ni < 4; ++ni)
                    acc[mi][ni] = __builtin_amdgcn_mfma_f32_16x16x32_bf16(af[mi], bf[ni], acc[mi][ni], 0, 0, 0);
        }
        __syncthreads();
    }

#pragma unroll
    for (int mi = 0; mi < 4; ++mi)
#pragma unroll
        for (int ni = 0; ni < 4; ++ni)
#pragma unroll
            for (int r = 0; r < 4; ++r) {
                int gr = m0 + wr*64 + mi*16 + 4*g + r;
                int gc = n0 + wc*64 + ni*16 + c;
                outf[(size_t)gr * DM + gc] = acc[mi][ni][r] + bias[gc];
            }
}

// ---------------- flash attention ----------------
// Validated round-7 structure, unrolled by 2 so buffer selection is
// compile-time: all 24 LDS fragment reads per tile = 4 hoisted per-lane base
// pointers + immediate offsets (y&7 == c&7 since nt*16 % 8 == 0).
// Staging globals strength-reduced to incremented pointers.
__global__ __launch_bounds__(256) void k_attn(const unsigned short* __restrict__ Q,
                                              const unsigned short* __restrict__ K,
                                              const unsigned short* __restrict__ VT,
                                              unsigned short* __restrict__ AO) {
    __shared__ unsigned short kt[2][64*64], vt[2][64*64];   // 32 KB
    int tid = threadIdx.x, lane = tid & 63, wv = tid >> 6;
    int c = lane & 15, g = lane >> 4;

    // XCD swizzle: 2048 blocks, 8 XCDs -> XCD x gets heads [8x, 8x+8)
    int flat = blockIdx.x;
    int nb = (flat & 7) * 256 + (flat >> 3);
    int qb = nb & 31, bh = nb >> 5;

    const unsigned short* Qh = Q  + (size_t)bh * SEQ * HD;
    const unsigned short* Kh = K  + (size_t)bh * SEQ * HD;
    const unsigned short* Vh = VT + (size_t)bh * HD * SEQ;

    int qrow = qb*64 + wv*16 + c;
    short8 qf0 = *reinterpret_cast<const short8*>(&Qh[(size_t)qrow*HD +      g*8]);
    short8 qf1 = *reinterpret_cast<const short8*>(&Qh[(size_t)qrow*HD + 32 + g*8]);

    // staging global pointers (incremented per tile)
    int row = tid >> 3, blk = tid & 7;
    int xo = (blk ^ (row & 7)) << 3;
    auto srowf = [](int r) {
        return ((r >> 4) & 1)*32 + ((r >> 2) & 3)*8 + ((r >> 5) & 1)*4 + (r & 3);
    };
    const unsigned short* gK0 = Kh + (size_t)srowf(row)      * HD + xo;
    const unsigned short* gK1 = Kh + (size_t)srowf(row + 32) * HD + xo;
    const unsigned short* gV0 = Vh + (size_t)row        * SEQ + xo;
    const unsigned short* gV1 = Vh + (size_t)(row + 32) * SEQ + xo;
    unsigned ldso = wv * 512;

    // hoisted LDS fragment-read bases (ushort units); buffer/nt via immediates
    int swz0 = (g ^ (c & 7)) << 3;
    int swz1 = ((4 + g) ^ (c & 7)) << 3;
    const unsigned short* kb0 = &kt[0][c*64 + swz0];
    const unsigned short* kb1 = &kt[0][c*64 + swz1];
    const unsigned short* vb0 = &vt[0][c*64 + swz0];
    const unsigned short* vb1 = &vt[0][c*64 + swz1];

    float m = -1e30f;
    f32x4 oacc[4] = {}, lacc = {};
    const short ob = (short)0x3F80;                 // bf16 1.0
    const short8 ones = {ob, ob, ob, ob, ob, ob, ob, ob};

#define STAGE(SB) do {                                                        \
        gload_lds16(gK0, &kt[SB][ldso]);                                      \
        gload_lds16(gK1, &kt[SB][2048 + ldso]);                               \
        gload_lds16(gV0, &vt[SB][ldso]);                                      \
        gload_lds16(gV1, &vt[SB][2048 + ldso]);                               \
        gK0 += 64*HD; gK1 += 64*HD; gV0 += 64; gV1 += 64;                     \
    } while (0)

#define TILE(BUFO, PRE) do {                                                  \
        PRE;                                                                  \
        f32x4 sacc[4] = {};                                                   \
        __builtin_amdgcn_s_setprio(1);                                        \
        _Pragma("unroll")                                                     \
        for (int nt = 0; nt < 4; ++nt) {                                      \
            short8 kf0 = *reinterpret_cast<const short8*>(kb0 + (BUFO) + nt*1024); \
            short8 kf1 = *reinterpret_cast<const short8*>(kb1 + (BUFO) + nt*1024); \
            sacc[nt] = __builtin_amdgcn_mfma_f32_16x16x32_bf16(kf0, qf0, sacc[nt], 0, 0, 0); \
            sacc[nt] = __builtin_amdgcn_mfma_f32_16x16x32_bf16(kf1, qf1, sacc[nt], 0, 0, 0); \
        }                                                                     \
        __builtin_amdgcn_s_setprio(0);                                        \
        float x0 = fmaxf(fmaxf(sacc[0][0], sacc[0][1]), sacc[0][2]);          \
        float x1 = fmaxf(fmaxf(sacc[0][3], sacc[1][0]), sacc[1][1]);          \
        float x2 = fmaxf(fmaxf(sacc[1][2], sacc[1][3]), sacc[2][0]);          \
        float x3 = fmaxf(fmaxf(sacc[2][1], sacc[2][2]), sacc[2][3]);          \
        float x4 = fmaxf(fmaxf(sacc[3][0], sacc[3][1]), sacc[3][2]);          \
        float tm = fmaxf(fmaxf(fmaxf(x0, x1), fmaxf(x2, x3)), fmaxf(x4, sacc[3][3])); \
        if (__any(tm > m + 8.0f)) {                                           \
            tm = fmaxf(tm, __shfl_xor(tm, 16, 64));                           \
            tm = fmaxf(tm, __shfl_xor(tm, 32, 64));                           \
            float mn = fmaxf(m, tm);                                          \
            float corr = __builtin_amdgcn_exp2f(m - mn);                      \
            m = mn; lacc *= corr;                                             \
            _Pragma("unroll")                                                 \
            for (int ft = 0; ft < 4; ++ft)                                    \
                _Pragma("unroll")                                             \
                for (int r = 0; r < 4; ++r) oacc[ft][r] *= corr;              \
        }                                                                     \
        _Pragma("unroll")                                                     \
        for (int nt = 0; nt < 4; ++nt)                                        \
            _Pragma("unroll")                                                 \
            for (int r = 0; r < 4; ++r)                                       \
                sacc[nt][r] = __builtin_amdgcn_exp2f(sacc[nt][r] - m);        \
        union { unsigned u[4]; short8 v; } U0, U1;                            \
        U0.u[0] = cvt_pk_bf16(sacc[0][0], sacc[0][1]);                        \
        U0.u[1] = cvt_pk_bf16(sacc[0][2], sacc[0][3]);                        \
        U0.u[2] = cvt_pk_bf16(sacc[2][0], sacc[2][1]);                        \
        U0.u[3] = cvt_pk_bf16(sacc[2][2], sacc[2][3]);                        \
        U1.u[0] = cvt_pk_bf16(sacc[1][0], sacc[1][1]);                        \
        U1.u[1] = cvt_pk_bf16(sacc[1][2], sacc[1][3]);                        \
        U1.u[2] = cvt_pk_bf16(sacc[3][0], sacc[3][1]);                        \
        U1.u[3] = cvt_pk_bf16(sacc[3][2], sacc[3][3]);                        \
        short8 pa0 = U0.v, pa1 = U1.v;                                        \
        __builtin_amdgcn_s_setprio(1);                                        \
        _Pragma("unroll")                                                     \
        for (int ft = 0; ft < 4; ++ft) {                                      \
            short8 vf0 = *reinterpret_cast<const short8*>(vb0 + (BUFO) + ft*1024); \
            short8 vf1 = *reinterpret_cast<const short8*>(vb1 + (BUFO) + ft*1024); \
            oacc[ft] = __builtin_amdgcn_mfma_f32_16x16x32_bf16(vf0, pa0, oacc[ft], 0, 0, 0); \
            oacc[ft] = __builtin_amdgcn_mfma_f32_16x16x32_bf16(vf1, pa1, oacc[ft], 0, 0, 0); \
        }                                                                     \
        lacc = __builtin_amdgcn_mfma_f32_16x16x32_bf16(ones, pa0, lacc, 0, 0, 0); \
        lacc = __builtin_amdgcn_mfma_f32_16x16x32_bf16(ones, pa1, lacc, 0, 0, 0); \
        __builtin_amdgcn_s_setprio(0);                                        \
        __syncthreads();                                                      \
    } while (0)

    STAGE(0);                 // t = 0 -> buf0
    __syncthreads();

    for (int tp = 0; tp < 15; ++tp) {
        TILE(0,    STAGE(1)); // compute t=2tp   (buf0), stage t=2tp+1 -> buf1
        TILE(4096, STAGE(0)); // compute t=2tp+1 (buf1), stage t=2tp+2 -> buf0
    }
    TILE(0,    STAGE(1));     // t = 30, stage t = 31 -> buf1
    TILE(4096, (void)0);      // t = 31, no stage

#undef STAGE
#undef TILE

    int b = bh >> 4, h = bh & 15;
    float inv = 1.f / lacc[0];
#pragma unroll
    for (int ft = 0; ft < 4; ++ft) {
        u16x4 o4;
#pragma unroll
        for (int r = 0; r < 4; ++r) o4[r] = f2b(oacc[ft][r] * inv);
        *reinterpret_cast<u16x4*>(
            &AO[(size_t)(b*SEQ + qrow) * DM + h*HD + ft*16 + 4*g]) = o4;
    }
}

extern "C" void kernel_launch(void* const* d_in, const int* in_sizes, int n_in,
                              void* d_out, int out_size, void* d_ws, size_t ws_size,
                              hipStream_t stream) {
    const float* x  = (const float*)d_in[0];
    const float* Wq = (const float*)d_in[1];
    const float* bq = (const float*)d_in[2];
    const float* Wk = (const float*)d_in[3];
    const float* bk = (const float*)d_in[4];
    const float* Wv = (const float*)d_in[5];
    const float* bv = (const float*)d_in[6];
    const float* Wo = (const float*)d_in[7];
    const float* bo = (const float*)d_in[8];

    char* ws = (char*)d_ws;
    unsigned short* xb  = (unsigned short*)(ws);                  // 16 MB
    unsigned short* wT  = (unsigned short*)(ws + (16u<<20));      //  8 MB (4 mats)
    unsigned short* Qb  = (unsigned short*)(ws + (24u<<20));      // 16 MB
    unsigned short* Kb  = (unsigned short*)(ws + (40u<<20));      // 16 MB
    unsigned short* VTb = (unsigned short*)(ws + (56u<<20));      // 16 MB
    unsigned short* AOb = (unsigned short*)(ws + (72u<<20));      // 16 MB

    k_cvt_x<<<dim3(MROWS*DM/8/256), 256, 0, stream>>>(x, xb);
    k_cvt_wT<<<dim3(16,16,4), 256, 0, stream>>>(Wq, Wk, Wv, Wo, wT);

    k_gemm_qkv<<<dim3(MROWS/BM, 3*DM/BN), 256, 0, stream>>>(xb, wT, bq, bk, bv, Qb, Kb, VTb);

    k_attn<<<dim3(SEQ/64 * BATCH*NH), 256, 0, stream>>>(Qb, Kb, VTb, AOb);

    k_gemm_o<<<dim3(MROWS/BM, DM/BN), 256, 0, stream>>>(AOb, wT + 3*DM*DM, bo, (float*)d_out);
}

// Round 10
// 197.704 us; speedup vs baseline: 1.2625x; 1.0098x over previous
//
#include <hip/hip_runtime.h>

#define DM 1024
#define NH 16
#define HD 64
#define SEQ 2048
#define BATCH 4
#define MROWS (BATCH*SEQ)   // 8192

typedef short short8 __attribute__((ext_vector_type(8)));
typedef float f32x4 __attribute__((ext_vector_type(4)));
typedef float f32x16 __attribute__((ext_vector_type(16)));
typedef unsigned short u16x8 __attribute__((ext_vector_type(8)));
typedef unsigned short u16x4 __attribute__((ext_vector_type(4)));

__device__ inline unsigned short f2b(float f) {
    union { float f; unsigned u; } v; v.f = f;
    unsigned r = v.u + 0x7fffu + ((v.u >> 16) & 1u);   // RNE
    return (unsigned short)(r >> 16);
}

__device__ inline void gload_lds16(const void* g, void* l) {
    __builtin_amdgcn_global_load_lds(
        (const __attribute__((address_space(1))) void*)g,
        (__attribute__((address_space(3))) void*)l, 16, 0, 0);
}

__device__ inline unsigned cvt_pk_bf16(float lo, float hi) {
    unsigned r;
    asm("v_cvt_pk_bf16_f32 %0, %1, %2" : "=v"(r) : "v"(lo), "v"(hi));
    return r;
}

// ---------------- convert x (fp32 -> bf16) ----------------
__global__ void k_cvt_x(const float* __restrict__ x, unsigned short* __restrict__ xb) {
    long i = ((long)blockIdx.x * 256 + threadIdx.x) * 8;
    float4 a = *reinterpret_cast<const float4*>(x + i);
    float4 b = *reinterpret_cast<const float4*>(x + i + 4);
    u16x8 o;
    o[0]=f2b(a.x); o[1]=f2b(a.y); o[2]=f2b(a.z); o[3]=f2b(a.w);
    o[4]=f2b(b.x); o[5]=f2b(b.y); o[6]=f2b(b.z); o[7]=f2b(b.w);
    *reinterpret_cast<u16x8*>(xb + i) = o;
}

// ---------------- convert + transpose W (fp32 [k][n] -> bf16 [n][k]) ----------------
__global__ void k_cvt_wT(const float* W0, const float* W1, const float* W2, const float* W3,
                         unsigned short* __restrict__ out) {
    const float* Ws[4] = {W0, W1, W2, W3};
    const float* W = Ws[blockIdx.z];
    unsigned short* o = out + (size_t)blockIdx.z * DM * DM;
    __shared__ float t[64][65];
    int tx = threadIdx.x & 15, ty = threadIdx.x >> 4;
    int nb = blockIdx.x * 64, kb = blockIdx.y * 64;
#pragma unroll
    for (int i = 0; i < 4; ++i) {
        int r = ty + 16 * i;
        float4 v = *reinterpret_cast<const float4*>(W + (size_t)(kb + r) * DM + nb + tx * 4);
        t[r][tx*4+0] = v.x; t[r][tx*4+1] = v.y; t[r][tx*4+2] = v.z; t[r][tx*4+3] = v.w;
    }
    __syncthreads();
#pragma unroll
    for (int i = 0; i < 4; ++i) {
        int r = ty + 16 * i;                  // n-local
        u16x4 pv;
#pragma unroll
        for (int j = 0; j < 4; ++j) pv[j] = f2b(t[tx*4+j][r]);
        *reinterpret_cast<u16x4*>(o + (size_t)(nb + r) * DM + kb + tx * 4) = pv;
    }
}

// ---------------- 128x128 bf16 MFMA GEMM ----------------
#define BM 128
#define BN 128
#define BK 64
#define QSCALE 0.1803368801f   // 0.125 * log2(e)

// Merged QKV GEMM: Bt = wT (Wq^T|Wk^T|Wv^T contiguous), N = 3072.
__global__ __launch_bounds__(256) void k_gemm_qkv(const unsigned short* __restrict__ A,
                                                  const unsigned short* __restrict__ WT,
                                                  const float* __restrict__ bq,
                                                  const float* __restrict__ bk,
                                                  const float* __restrict__ bv,
                                                  unsigned short* __restrict__ Qb,
                                                  unsigned short* __restrict__ Kb,
                                                  unsigned short* __restrict__ VTb) {
    __shared__ unsigned short lds[BM*BK + BN*BK];   // 32 KB
    unsigned short* lA = lds;
    unsigned short* lB = lds + BM*BK;
    int tid = threadIdx.x, lane = tid & 63, wv = tid >> 6;
    int wr = wv >> 1, wc = wv & 1;
    int c = lane & 15, g = lane >> 4;
    int m0 = blockIdx.x * BM, n0 = blockIdx.y * BN;
    f32x4 acc[4][4] = {};

    for (int kt = 0; kt < DM / BK; ++kt) {
#pragma unroll
        for (int it = 0; it < 4; ++it) {
            int sgi = it * 256 + tid;
            int row = sgi >> 3, blk = sgi & 7;
            int srcoff = kt * BK + ((blk ^ (row & 7)) << 3);
            gload_lds16(A  + (size_t)(m0 + row) * DM + srcoff, &lA[(it*256 + wv*64) * 8]);
            gload_lds16(WT + (size_t)(n0 + row) * DM + srcoff, &lB[(it*256 + wv*64) * 8]);
        }
        __syncthreads();
#pragma unroll
        for (int ks = 0; ks < 2; ++ks) {
            short8 af[4], bf[4];
#pragma unroll
            for (int mi = 0; mi < 4; ++mi) {
                int row = wr*64 + mi*16 + c;
                af[mi] = *reinterpret_cast<const short8*>(&lA[row*64 + (((ks*4 + g) ^ (row & 7)) << 3)]);
            }
#pragma unroll
            for (int ni = 0; ni < 4; ++ni) {
                int row = wc*64 + ni*16 + c;
                bf[ni] = *reinterpret_cast<const short8*>(&lB[row*64 + (((ks*4 + g) ^ (row & 7)) << 3)]);
            }
#pragma unroll
            for (int mi = 0; mi < 4; ++mi)
#pragma unroll
                for (int ni = 0; ni < 4; ++ni)
                    acc[mi][ni] = __builtin_amdgcn_mfma_f32_16x16x32_bf16(af[mi], bf[ni], acc[mi][ni], 0, 0, 0);
        }
        __syncthreads();
    }

    int mat = n0 >> 10;                       // 0=Q 1=K 2=V (block-uniform)
    int gb = n0 & 1023;                       // column base within the mat
    const float* bias = (mat == 0) ? bq : (mat == 1) ? bk : bv;

    if (mat < 2) {                            // Q / K -> [B,H,S,Hd] bf16 (Q pre-scaled)
        unsigned short* outb = (mat == 0) ? Qb : Kb;
        float sc = (mat == 0) ? QSCALE : 1.0f;
#pragma unroll
        for (int mi = 0; mi < 4; ++mi)
#pragma unroll
            for (int ni = 0; ni < 4; ++ni)
#pragma unroll
                for (int r = 0; r < 4; ++r) {
                    int gr = m0 + wr*64 + mi*16 + 4*g + r;
                    int gc = gb + wc*64 + ni*16 + c;
                    float v = (acc[mi][ni][r] + bias[gc]) * sc;
                    int b = gr >> 11, s = gr & 2047, h = gc >> 6, d = gc & 63;
                    outb[(((size_t)(b*NH + h) * SEQ + s) << 6) + d] = f2b(v);
                }
    } else {                                  // V^T -> [B,H,Hd,S] bf16 via LDS transpose
        unsigned short* t = lds;              // 128x128 ushorts = 32 KB exactly
#pragma unroll
        for (int mi = 0; mi < 4; ++mi)
#pragma unroll
            for (int ni = 0; ni < 4; ++ni)
#pragma unroll
                for (int r = 0; r < 4; ++r) {
                    int lr = wr*64 + mi*16 + 4*g + r;   // s-local
                    int lc = wc*64 + ni*16 + c;         // col-local
                    t[lc*128 + lr] = f2b(acc[mi][ni][r] + bias[gb + lc]);
                }
        __syncthreads();
#pragma unroll
        for (int i = 0; i < 8; ++i) {
            int idx = (i*256 + tid) * 8;          // ushort offset in t
            int lc = idx >> 7, lr = idx & 127;
            int gcol = gb + lc, grow = m0 + lr;
            int b = grow >> 11, s = grow & 2047, h = gcol >> 6, d = gcol & 63;
            *reinterpret_cast<u16x8*>(&VTb[((size_t)((b*NH + h) << 6) + d) * SEQ + s]) =
                *reinterpret_cast<u16x8*>(&t[idx]);
        }
    }
}

// Final projection GEMM: out fp32 + bias
__global__ __launch_bounds__(256) void k_gemm_o(const unsigned short* __restrict__ A,
                                                const unsigned short* __restrict__ Bt,
                                                const float* __restrict__ bias,
                                                float* __restrict__ outf) {
    __shared__ unsigned short lds[BM*BK + BN*BK];   // 32 KB
    unsigned short* lA = lds;
    unsigned short* lB = lds + BM*BK;
    int tid = threadIdx.x, lane = tid & 63, wv = tid >> 6;
    int wr = wv >> 1, wc = wv & 1;
    int c = lane & 15, g = lane >> 4;
    int m0 = blockIdx.x * BM, n0 = blockIdx.y * BN;
    f32x4 acc[4][4] = {};

    for (int kt = 0; kt < DM / BK; ++kt) {
#pragma unroll
        for (int it = 0; it < 4; ++it) {
            int sgi = it * 256 + tid;
            int row = sgi >> 3, blk = sgi & 7;
            int srcoff = kt * BK + ((blk ^ (row & 7)) << 3);
            gload_lds16(A  + (size_t)(m0 + row) * DM + srcoff, &lA[(it*256 + wv*64) * 8]);
            gload_lds16(Bt + (size_t)(n0 + row) * DM + srcoff, &lB[(it*256 + wv*64) * 8]);
        }
        __syncthreads();
#pragma unroll
        for (int ks = 0; ks < 2; ++ks) {
            short8 af[4], bf[4];
#pragma unroll
            for (int mi = 0; mi < 4; ++mi) {
                int row = wr*64 + mi*16 + c;
                af[mi] = *reinterpret_cast<const short8*>(&lA[row*64 + (((ks*4 + g) ^ (row & 7)) << 3)]);
            }
#pragma unroll
            for (int ni = 0; ni < 4; ++ni) {
                int row = wc*64 + ni*16 + c;
                bf[ni] = *reinterpret_cast<const short8*>(&lB[row*64 + (((ks*4 + g) ^ (row & 7)) << 3)]);
            }
#pragma unroll
            for (int mi = 0; mi < 4; ++mi)
#pragma unroll
                for (int ni = 0; ni < 4; ++ni)
                    acc[mi][ni] = __builtin_amdgcn_mfma_f32_16x16x32_bf16(af[mi], bf[ni], acc[mi][ni], 0, 0, 0);
        }
        __syncthreads();
    }

#pragma unroll
    for (int mi = 0; mi < 4; ++mi)
#pragma unroll
        for (int ni = 0; ni < 4; ++ni)
#pragma unroll
            for (int r = 0; r < 4; ++r) {
                int gr = m0 + wr*64 + mi*16 + 4*g + r;
                int gc = n0 + wc*64 + ni*16 + c;
                outf[(size_t)gr * DM + gc] = acc[mi][ni][r] + bias[gc];
            }
}

// ---------------- flash attention (32x32x16 MFMA, P in registers) ----------------
// 4 waves x 32 q-rows; KV tile 64; 2-buffer __syncthreads skeleton (validated).
// Swapped QK: lane (q5,hi) holds scores S[crow(r,hi)][q5]; P -> PV B-fragments
// via cvt_pk + v_permlane32_swap with the CORRECT routing:
//   a = pk(s[b+0],s[b+1]); b_ = pk(s[b+4],s[b+5]); swap(a,b_); u[0]=a; u[2]=b_.
__global__ __launch_bounds__(256) void k_attn(const unsigned short* __restrict__ Q,
                                              const unsigned short* __restrict__ K,
                                              const unsigned short* __restrict__ VT,
                                              unsigned short* __restrict__ AO) {
    __shared__ unsigned short sm[4][64*64];   // [0..1]=K bufs, [2..3]=V bufs; 32 KB
    int tid = threadIdx.x, lane = tid & 63, wv = tid >> 6;
    int q5 = lane & 31, hi = lane >> 5;

    // XCD swizzle: 1024 blocks, 8 XCDs -> XCD x gets heads [8x, 8x+8)
    int flat = blockIdx.x;
    int nb = (flat & 7) * 128 + (flat >> 3);
    int qb = nb & 15, bh = nb >> 4;

    const unsigned short* Qh = Q  + (size_t)bh * SEQ * HD;
    const unsigned short* Kh = K  + (size_t)bh * SEQ * HD;
    const unsigned short* Vh = VT + (size_t)bh * HD * SEQ;

    int qrow = qb*128 + wv*32 + q5;
    // Q B-fragments: qf[s] = Q[qrow][16s + 8hi .. +8]
    short8 qf0 = *reinterpret_cast<const short8*>(&Qh[(size_t)qrow*HD +  0 + hi*8]);
    short8 qf1 = *reinterpret_cast<const short8*>(&Qh[(size_t)qrow*HD + 16 + hi*8]);
    short8 qf2 = *reinterpret_cast<const short8*>(&Qh[(size_t)qrow*HD + 32 + hi*8]);
    short8 qf3 = *reinterpret_cast<const short8*>(&Qh[(size_t)qrow*HD + 48 + hi*8]);

    // staging pointers (linear rows, XOR-8 chunk swizzle pre-applied on source)
    int row = tid >> 3, blk = tid & 7;
    int xo = (blk ^ (row & 7)) << 3;
    const unsigned short* gK0 = Kh + (size_t)row        * HD + xo;
    const unsigned short* gK1 = Kh + (size_t)(row + 32) * HD + xo;
    const unsigned short* gV0 = Vh + (size_t)row        * SEQ + xo;
    const unsigned short* gV1 = Vh + (size_t)(row + 32) * SEQ + xo;
    unsigned ldso = wv * 512;

    // fragment-read pointers: subtile s reads 16B chunk ((2s+hi)^(q5&7)) of row q5
    const char* P0; const char* P1; const char* P2; const char* P3;
    {
        int o0 = (hi ^ (q5 & 7)) << 4;
        const char* base = (const char*)&sm[0][0] + q5*128;
        P0 = base + (o0 ^ 0);
        P1 = base + (o0 ^ 32);
        P2 = base + (o0 ^ 64);
        P3 = base + (o0 ^ 96);
    }
    // imm offsets from P_s: K: buf*8192 + kblk*4096 ; V: 16384 + buf*8192 + dblk*4096

    float m = -1e30f;
    f32x16 o0acc = {}, o1acc = {}, lacc = {};
    const short ob = (short)0x3F80;                 // bf16 1.0
    const short8 ones = {ob, ob, ob, ob, ob, ob, ob, ob};

#define STAGE(SB) do {                                                        \
        gload_lds16(gK0, &sm[SB][ldso]);                                      \
        gload_lds16(gK1, &sm[SB][2048 + ldso]);                               \
        gload_lds16(gV0, &sm[2 + (SB)][ldso]);                                \
        gload_lds16(gV1, &sm[2 + (SB)][2048 + ldso]);                         \
        gK0 += 64*HD; gK1 += 64*HD; gV0 += 64; gV1 += 64;                     \
    } while (0)

#define RD8(P, OFF) (*reinterpret_cast<const short8*>((P) + (OFF)))

#define MKFRAG(F, SLO0, SLO1, SLO2, SLO3, SHI0, SHI1, SHI2, SHI3) do {        \
        unsigned a0 = cvt_pk_bf16(SLO0, SLO1);                                \
        unsigned b0 = cvt_pk_bf16(SHI0, SHI1);                                \
        asm("v_permlane32_swap_b32 %0, %1" : "+v"(a0), "+v"(b0));             \
        F.u[0] = a0; F.u[2] = b0;                                             \
        unsigned a1 = cvt_pk_bf16(SLO2, SLO3);                                \
        unsigned b1 = cvt_pk_bf16(SHI2, SHI3);                                \
        asm("v_permlane32_swap_b32 %0, %1" : "+v"(a1), "+v"(b1));             \
        F.u[1] = a1; F.u[3] = b1;                                             \
    } while (0)

#define TILE(BUFO, PRE) do {                                                  \
        PRE;                                                                  \
        f32x16 s0 = {}, s1 = {};                                              \
        __builtin_amdgcn_s_setprio(1);                                        \
        s0 = __builtin_amdgcn_mfma_f32_32x32x16_bf16(RD8(P0, BUFO),      qf0, s0, 0, 0, 0); \
        s1 = __builtin_amdgcn_mfma_f32_32x32x16_bf16(RD8(P0, BUFO+4096), qf0, s1, 0, 0, 0); \
        s0 = __builtin_amdgcn_mfma_f32_32x32x16_bf16(RD8(P1, BUFO),      qf1, s0, 0, 0, 0); \
        s1 = __builtin_amdgcn_mfma_f32_32x32x16_bf16(RD8(P1, BUFO+4096), qf1, s1, 0, 0, 0); \
        s0 = __builtin_amdgcn_mfma_f32_32x32x16_bf16(RD8(P2, BUFO),      qf2, s0, 0, 0, 0); \
        s1 = __builtin_amdgcn_mfma_f32_32x32x16_bf16(RD8(P2, BUFO+4096), qf2, s1, 0, 0, 0); \
        s0 = __builtin_amdgcn_mfma_f32_32x32x16_bf16(RD8(P3, BUFO),      qf3, s0, 0, 0, 0); \
        s1 = __builtin_amdgcn_mfma_f32_32x32x16_bf16(RD8(P3, BUFO+4096), qf3, s1, 0, 0, 0); \
        __builtin_amdgcn_s_setprio(0);                                        \
        float x0 = fmaxf(fmaxf(s0[0],  s0[1]),  s0[2]);                       \
        float x1 = fmaxf(fmaxf(s0[3],  s0[4]),  s0[5]);                       \
        float x2 = fmaxf(fmaxf(s0[6],  s0[7]),  s0[8]);                       \
        float x3 = fmaxf(fmaxf(s0[9],  s0[10]), s0[11]);                      \
        float x4 = fmaxf(fmaxf(s0[12], s0[13]), s0[14]);                      \
        float x5 = fmaxf(fmaxf(s0[15], s1[0]),  s1[1]);                       \
        float x6 = fmaxf(fmaxf(s1[2],  s1[3]),  s1[4]);                       \
        float x7 = fmaxf(fmaxf(s1[5],  s1[6]),  s1[7]);                       \
        float x8 = fmaxf(fmaxf(s1[8],  s1[9]),  s1[10]);                      \
        float x9 = fmaxf(fmaxf(s1[11], s1[12]), s1[13]);                      \
        float y  = fmaxf(s1[14], s1[15]);                                     \
        float z0 = fmaxf(fmaxf(x0, x1), x2);                                  \
        float z1 = fmaxf(fmaxf(x3, x4), x5);                                  \
        float z2 = fmaxf(fmaxf(x6, x7), x8);                                  \
        float tm = fmaxf(fmaxf(fmaxf(z0, z1), z2), fmaxf(x9, y));             \
        if (__any(tm > m + 8.0f)) {                                           \
            float fl = fmaxf(tm, __shfl_xor(tm, 32, 64));                     \
            float mn = fmaxf(m, fl);                                          \
            float corr = __builtin_amdgcn_exp2f(m - mn);                      \
            m = mn; lacc[0] *= corr;                                          \
            _Pragma("unroll")                                                 \
            for (int r = 0; r < 16; ++r) { o0acc[r] *= corr; o1acc[r] *= corr; } \
        }                                                                     \
        _Pragma("unroll")                                                     \
        for (int r = 0; r < 16; ++r) {                                        \
            s0[r] = __builtin_amdgcn_exp2f(s0[r] - m);                        \
            s1[r] = __builtin_amdgcn_exp2f(s1[r] - m);                        \
        }                                                                     \
        union { unsigned u[4]; short8 v; } F0, F1, F2, F3;                    \
        MKFRAG(F0, s0[0],  s0[1],  s0[2],  s0[3],  s0[4],  s0[5],  s0[6],  s0[7]);  \
        MKFRAG(F1, s0[8],  s0[9],  s0[10], s0[11], s0[12], s0[13], s0[14], s0[15]); \
        MKFRAG(F2, s1[0],  s1[1],  s1[2],  s1[3],  s1[4],  s1[5],  s1[6],  s1[7]);  \
        MKFRAG(F3, s1[8],  s1[9],  s1[10], s1[11], s1[12], s1[13], s1[14], s1[15]); \
        __builtin_amdgcn_s_setprio(1);                                        \
        o0acc = __builtin_amdgcn_mfma_f32_32x32x16_bf16(RD8(P0, 16384+BUFO),      F0.v, o0acc, 0, 0, 0); \
        o1acc = __builtin_amdgcn_mfma_f32_32x32x16_bf16(RD8(P0, 16384+BUFO+4096), F0.v, o1acc, 0, 0, 0); \
        lacc  = __builtin_amdgcn_mfma_f32_32x32x16_bf16(ones, F0.v, lacc, 0, 0, 0); \
        o0acc = __builtin_amdgcn_mfma_f32_32x32x16_bf16(RD8(P1, 16384+BUFO),      F1.v, o0acc, 0, 0, 0); \
        o1acc = __builtin_amdgcn_mfma_f32_32x32x16_bf16(RD8(P1, 16384+BUFO+4096), F1.v, o1acc, 0, 0, 0); \
        lacc  = __builtin_amdgcn_mfma_f32_32x32x16_bf16(ones, F1.v, lacc, 0, 0, 0); \
        o0acc = __builtin_amdgcn_mfma_f32_32x32x16_bf16(RD8(P2, 16384+BUFO),      F2.v, o0acc, 0, 0, 0); \
        o1acc = __builtin_amdgcn_mfma_f32_32x32x16_bf16(RD8(P2, 16384+BUFO+4096), F2.v, o1acc, 0, 0, 0); \
        lacc  = __builtin_amdgcn_mfma_f32_32x32x16_bf16(ones, F2.v, lacc, 0, 0, 0); \
        o0acc = __builtin_amdgcn_mfma_f32_32x32x16_bf16(RD8(P3, 16384+BUFO),      F3.v, o0acc, 0, 0, 0); \
        o1acc = __builtin_amdgcn_mfma_f32_32x32x16_bf16(RD8(P3, 16384+BUFO+4096), F3.v, o1acc, 0, 0, 0); \
        lacc  = __builtin_amdgcn_mfma_f32_32x32x16_bf16(ones, F3.v, lacc, 0, 0, 0); \
        __builtin_amdgcn_s_setprio(0);                                        \
        __syncthreads();                                                      \
    } while (0)

    STAGE(0);                 // t = 0 -> buf0
    __syncthreads();

    for (int tp = 0; tp < 15; ++tp) {
        TILE(0,    STAGE(1)); // compute t=2tp   (buf0), stage t=2tp+1 -> buf1
        TILE(8192, STAGE(0)); // compute t=2tp+1 (buf1), stage t=2tp+2 -> buf0
    }
    TILE(0,    STAGE(1));     // t = 30, stage t = 31 -> buf1
    TILE(8192, (void)0);      // t = 31, no stage

#undef STAGE
#undef TILE
#undef RD8
#undef MKFRAG

    int b = bh >> 4, h = bh & 15;
    float inv = 1.f / lacc[0];
    unsigned short* aob = &AO[(size_t)(b*SEQ + qrow) * DM + h*HD];
#pragma unroll
    for (int rg = 0; rg < 4; ++rg) {
        u16x4 oa, obv;
#pragma unroll
        for (int j = 0; j < 4; ++j) {
            oa[j]  = f2b(o0acc[rg*4 + j] * inv);
            obv[j] = f2b(o1acc[rg*4 + j] * inv);
        }
        *reinterpret_cast<u16x4*>(aob + rg*8 + hi*4)      = oa;   // d = rg*8+4hi+j
        *reinterpret_cast<u16x4*>(aob + 32 + rg*8 + hi*4) = obv;  // d = 32+rg*8+4hi+j
    }
}

extern "C" void kernel_launch(void* const* d_in, const int* in_sizes, int n_in,
                              void* d_out, int out_size, void* d_ws, size_t ws_size,
                              hipStream_t stream) {
    const float* x  = (const float*)d_in[0];
    const float* Wq = (const float*)d_in[1];
    const float* bq = (const float*)d_in[2];
    const float* Wk = (const float*)d_in[3];
    const float* bk = (const float*)d_in[4];
    const float* Wv = (const float*)d_in[5];
    const float* bv = (const float*)d_in[6];
    const float* Wo = (const float*)d_in[7];
    const float* bo = (const float*)d_in[8];

    char* ws = (char*)d_ws;
    unsigned short* xb  = (unsigned short*)(ws);                  // 16 MB
    unsigned short* wT  = (unsigned short*)(ws + (16u<<20));      //  8 MB (4 mats)
    unsigned short* Qb  = (unsigned short*)(ws + (24u<<20));      // 16 MB
    unsigned short* Kb  = (unsigned short*)(ws + (40u<<20));      // 16 MB
    unsigned short* VTb = (unsigned short*)(ws + (56u<<20));      // 16 MB
    unsigned short* AOb = (unsigned short*)(ws + (72u<<20));      // 16 MB

    k_cvt_x<<<dim3(MROWS*DM/8/256), 256, 0, stream>>>(x, xb);
    k_cvt_wT<<<dim3(16,16,4), 256, 0, stream>>>(Wq, Wk, Wv, Wo, wT);

    k_gemm_qkv<<<dim3(MROWS/BM, 3*DM/BN), 256, 0, stream>>>(xb, wT, bq, bk, bv, Qb, Kb, VTb);

    k_attn<<<dim3(SEQ/128 * BATCH*NH), 256, 0, stream>>>(Qb, Kb, VTb, AOb);

    k_gemm_o<<<dim3(MROWS/BM, DM/BN), 256, 0, stream>>>(AOb, wT + 3*DM*DM, bo, (float*)d_out);
}